// Round 9
// baseline (248.967 us; speedup 1.0000x reference)
//
#include <hip/hip_runtime.h>
#include <hip/hip_bf16.h>
#include <hip/hip_fp16.h>

#define N_TRAIN 200000
#define DIMS    64
#define NQ      1024
#define KSEL    32
#define NCLS    10

#define CHROWS2 391     // rows per chunk; 512*391 >= 200000
#define NCHUNK  512
#define NBLK0   1024    // k_dist<0> grid: chunk = bid>>1, query-half = bid&1
#define LCAP    8       // per-(block, query) pool cap
#define OVFCAP  256     // per-query overflow cap
#define TOTC    4096    // merge candidate cap per query
#define MAXS    1536    // merge survivor cap per query
#define SAMPLES 8192
#define SROWS   32      // sample rows per k_dist<1> block
#define NPB     3125    // k_prep blocks

typedef float f32x4 __attribute__((ext_vector_type(4)));
typedef short f16x8 __attribute__((ext_vector_type(8)));

__device__ __forceinline__ unsigned fmap(float f) {
    unsigned u = __float_as_uint(f);
    return u ^ ((u >> 31) ? 0xFFFFFFFFu : 0x80000000u);
}
__device__ __forceinline__ float funmap(unsigned m) {
    unsigned u = m ^ ((m >> 31) ? 0x80000000u : 0xFFFFFFFFu);
    return __uint_as_float(u);
}
__device__ __forceinline__ unsigned short f2h(float f) {   // RNE f32->f16 bits
    union { __half h; unsigned short u; } c;
    c.h = __float2half_rn(f);
    return c.u;
}
__device__ __forceinline__ f16x8 pack8h(float4 a, float4 b) {
    f16x8 r;
    r[0] = (short)f2h(a.x); r[1] = (short)f2h(a.y);
    r[2] = (short)f2h(a.z); r[3] = (short)f2h(a.w);
    r[4] = (short)f2h(b.x); r[5] = (short)f2h(b.y);
    r[6] = (short)f2h(b.z); r[7] = (short)f2h(b.w);
    return r;
}

// ---------------- fused: x2 = ||x||^2, per-block max, X -> f16 (one X read)
__global__ __launch_bounds__(512) void k_prep(const float* __restrict__ X,
                                              float* __restrict__ x2,
                                              float* __restrict__ bmax,
                                              short* __restrict__ Xh) {
    int T = blockIdx.x * 512 + threadIdx.x;   // 8 threads per row
    int row = T >> 3;
    int l8 = T & 7;
    const float4* xp = (const float4*)(X + (long)row * 64 + l8 * 8);
    float4 a = xp[0], b = xp[1];
    *(f16x8*)(Xh + (long)row * 64 + l8 * 8) = pack8h(a, b);
    float p = a.x * a.x + a.y * a.y + a.z * a.z + a.w * a.w +
              b.x * b.x + b.y * b.y + b.z * b.z + b.w * b.w;
    p += __shfl_xor(p, 1);
    p += __shfl_xor(p, 2);
    p += __shfl_xor(p, 4);
    if (l8 == 0) x2[row] = p;
    float m = p;
    m = fmaxf(m, __shfl_xor(m, 8));
    m = fmaxf(m, __shfl_xor(m, 16));
    m = fmaxf(m, __shfl_xor(m, 32));
    __shared__ float wm[8];
    if ((threadIdx.x & 63) == 0) wm[threadIdx.x >> 6] = m;
    __syncthreads();
    if (threadIdx.x == 0) {
        float r = wm[0];
#pragma unroll
        for (int i = 1; i < 8; i++) r = fmaxf(r, wm[i]);
        bmax[blockIdx.x] = r;
    }
}

__global__ __launch_bounds__(256) void k_max(const float* __restrict__ bmax,
                                             float* __restrict__ x2maxf) {
    float m = -1e30f;
    for (int i = threadIdx.x; i < NPB; i += 256) m = fmaxf(m, bmax[i]);
#pragma unroll
    for (int d = 1; d < 64; d <<= 1) m = fmaxf(m, __shfl_xor(m, d));
    __shared__ float wm[4];
    if ((threadIdx.x & 63) == 0) wm[threadIdx.x >> 6] = m;
    __syncthreads();
    if (threadIdx.x == 0)
        *x2maxf = fmaxf(fmaxf(wm[0], wm[1]), fmaxf(wm[2], wm[3]));
}

// ---------------- Q f32 -> f16
__global__ __launch_bounds__(256) void k_cvt(const float* __restrict__ src,
                                             short* __restrict__ dst) {
    long c = (long)blockIdx.x * 256 + threadIdx.x;
    const float4* xp = (const float4*)(src + c * 8);
    float4 a = xp[0], b = xp[1];
    *(f16x8*)(dst + c * 8) = pack8h(a, b);
}

// ================================================================ k_dist
// 512 threads = 8 waves; wave w owns 64 queries (4 MFMA tiles, A-frags in reg).
// Block covers query half (bid&1); chunk = bid>>1. Register prefetch of the
// next 16-row group's B-fragments hides load latency; no LDS staging, no
// barriers in the main loop.
// MODE 1: 512 blocks (2 x 256): 32 sample rows -> packed u16 keys.
// MODE 0: 1024 blocks: 391 rows -> LDS candidate pools, coalesced flush.
template<int MODE>
__global__ __launch_bounds__(512) void k_dist(
    const short* __restrict__ Xh, const short* __restrict__ Qh,
    const float* __restrict__ x2, const float* __restrict__ tqw,
    unsigned* __restrict__ pcnt, unsigned* __restrict__ pool,
    unsigned* __restrict__ ovfcnt, uint2* __restrict__ ovf,
    unsigned short* __restrict__ keys) {
    int bid = blockIdx.x;
    int tid = threadIdx.x;
    int qh = bid & 1;           // query half
    int cb = bid >> 1;          // row chunk
    int w = tid >> 6;           // wave 0..7
    int lane = tid & 63;
    int lr = lane & 15;
    int lk = lane >> 4;

    __shared__ unsigned lcnt[MODE == 0 ? 512 : 1];
    __shared__ unsigned lbuf[MODE == 0 ? 512 * LCAP : 1];

    int r0 = MODE ? cb * SROWS : cb * CHROWS2;
    int rowEnd = MODE ? (r0 + SROWS) : min(r0 + CHROWS2, N_TRAIN);

    if (MODE == 0) {
        lcnt[tid] = 0u;        // tid < 512 covers all
        __syncthreads();
    }

    int qbase = (qh << 9) + (w << 6);   // global query base for this wave

    // A fragments: 64 queries = 4 tiles of 16
    f16x8 afr[4][2];
#pragma unroll
    for (int qi = 0; qi < 4; qi++) {
        const short* qp = Qh + (long)(qbase + (qi << 4) + lr) * 64 + (lk << 3);
        afr[qi][0] = *(const f16x8*)qp;
        afr[qi][1] = *(const f16x8*)(qp + 32);
    }
    float htq[4];
    if (MODE == 0) {
#pragma unroll
        for (int qi = 0; qi < 4; qi++) {
            float4 t4 = *(const float4*)(tqw + qbase + (qi << 4) + (lk << 2));
            htq[qi] = 0.5f * fmaxf(fmaxf(t4.x, t4.y), fmaxf(t4.z, t4.w));
        }
    }

    // register prefetch pipeline over 16-row groups
    f16x8 cb0, cb1;
    float cx2;
    {
        int rowc = min(r0 + lr, rowEnd - 1);
        const short* xp = Xh + (long)rowc * 64 + (lk << 3);
        cb0 = *(const f16x8*)xp;
        cb1 = *(const f16x8*)(xp + 32);
        cx2 = (r0 + lr < rowEnd) ? x2[rowc] : 1e30f;
    }

    for (int base = r0; base < rowEnd; base += 16) {
        f16x8 b0 = cb0, b1 = cb1;
        float x2c = cx2;
        int nb = base + 16;
        if (nb < rowEnd) {                       // issue next group's loads now
            int rowc = min(nb + lr, rowEnd - 1);
            const short* xp = Xh + (long)rowc * 64 + (lk << 3);
            cb0 = *(const f16x8*)xp;
            cb1 = *(const f16x8*)(xp + 32);
            cx2 = (nb + lr < rowEnd) ? x2[rowc] : 1e30f;
        }
        int row = base + lr;
        bool valid = row < rowEnd;
        float hx = 0.5f * x2c;

#pragma unroll
        for (int qi = 0; qi < 4; qi++) {
            f32x4 acc = {0.f, 0.f, 0.f, 0.f};
            acc = __builtin_amdgcn_mfma_f32_16x16x32_f16(afr[qi][0], b0, acc, 0, 0, 0);
            acc = __builtin_amdgcn_mfma_f32_16x16x32_f16(afr[qi][1], b1, acc, 0, 0, 0);
            if (MODE == 1) {
#pragma unroll
                for (int r4 = 0; r4 < 4; r4++) {
                    unsigned k16 = fmap(x2c - 2.f * acc[r4]) >> 16;
                    unsigned o = (unsigned)__shfl_xor((int)k16, 1);
                    unsigned v2 = k16 | (o << 16);                  // rows lr,lr+1
                    unsigned p2 = (unsigned)__shfl_xor((int)v2, 2); // rows lr+2,lr+3
                    if ((lr & 3) == 0) {
                        int qg = qbase + (qi << 4) + (lk << 2) + r4;
                        *(uint2*)(&keys[(long)qg * SAMPLES + row]) = make_uint2(v2, p2);
                    }
                }
            } else {
                float mx = fmaxf(fmaxf(acc[0], acc[1]), fmaxf(acc[2], acc[3]));
                if (valid && mx + htq[qi] >= hx) {     // sound quick reject
                    float4 t4 = *(const float4*)(tqw + qbase + (qi << 4) + (lk << 2));
                    float tq4[4] = {t4.x, t4.y, t4.z, t4.w};
#pragma unroll
                    for (int r4 = 0; r4 < 4; r4++) {
                        if (acc[r4] + 0.5f * tq4[r4] >= hx) {
                            int qg = qbase + (qi << 4) + (lk << 2) + r4;
                            int ql = qg & 511;
                            // 23-bit approx key + 9-bit local row
                            unsigned entry = (fmap(x2c - 2.f * acc[r4]) & 0xFFFFFE00u) |
                                             (unsigned)(row - r0);
                            unsigned slot = atomicAdd(&lcnt[ql], 1u);
                            if (slot < LCAP) {
                                lbuf[ql * LCAP + slot] = entry;
                            } else {   // rare overflow: per-query global pool
                                unsigned o = atomicAdd(&ovfcnt[qg], 1u);
                                if (o < OVFCAP)
                                    ovf[qg * OVFCAP + o] =
                                        make_uint2(entry >> 9, (unsigned)row);
                            }
                        }
                    }
                }
            }
        }
    }

    if (MODE == 0) {   // coalesced flush: no global atomics, dense 32B per (bid,ql)
        __syncthreads();
        int ql = tid;  // 512 threads = 512 queries
        unsigned lc = min(lcnt[ql], (unsigned)LCAP);
        pcnt[((long)bid << 9) + ql] = lc;
        uint4 a = *(uint4*)&lbuf[ql * LCAP];
        uint4 b = *(uint4*)&lbuf[ql * LCAP + 4];
        long base = (((long)bid << 9) + ql) * LCAP;
        *(uint4*)&pool[base] = a;              // garbage beyond lc never read
        *(uint4*)&pool[base + 4] = b;
    }
}

// ---------------- 32nd-smallest sample key -> widened threshold (f16 bound)
__global__ __launch_bounds__(256) void k_sel(const unsigned short* __restrict__ keys,
                                             const float* __restrict__ Qm,
                                             const float* __restrict__ x2maxf,
                                             float* __restrict__ tqw,
                                             float* __restrict__ q2g) {
    int q = blockIdx.x, tid = threadIdx.x;
    unsigned short mk[32];
#pragma unroll
    for (int m = 0; m < 32; m++) mk[m] = keys[(long)q * SAMPLES + tid + 256 * m];
    __shared__ float q2s_;
    __shared__ int cnt;
    if (tid < 64) {
        float v = Qm[(long)q * 64 + tid];
        float p = v * v;
#pragma unroll
        for (int d = 1; d < 64; d <<= 1) p += __shfl_xor(p, d);
        if (tid == 0) q2s_ = p;
    }
    unsigned lo = 0, hi = 65535;
    for (int it = 0; it < 16; ++it) {
        __syncthreads();
        if (tid == 0) cnt = 0;
        __syncthreads();
        unsigned mid = (lo + hi) >> 1;
        int c = 0;
#pragma unroll
        for (int m = 0; m < 32; m++) c += (mk[m] <= mid) ? 1 : 0;
#pragma unroll
        for (int d = 1; d < 64; d <<= 1) c += __shfl_xor(c, d);
        if ((tid & 63) == 0) atomicAdd(&cnt, c);
        __syncthreads();
        if (cnt >= KSEL) hi = mid; else lo = mid + 1;
    }
    if (tid == 0) {
        unsigned vv = hi + 2u; if (vv > 65535u) vv = 65535u;
        float t = funmap(vv << 16);
        float q2 = q2s_;
        // widen: 2x f16 dot-error bound + margin
        tqw[q] = t + 0.004f * sqrtf(q2 * (*x2maxf)) + 0.1f;
        q2g[q] = q2;
    }
}

// ---------------- approx-cut (23-bit) -> exact re-rank survivors -> vote
__global__ __launch_bounds__(256) void k_merge(const float* __restrict__ Qm,
                                               const float* __restrict__ X,
                                               const float* __restrict__ x2,
                                               const int* __restrict__ labels,
                                               const unsigned* __restrict__ pcnt,
                                               const unsigned* __restrict__ pool,
                                               const unsigned* __restrict__ ovfcnt,
                                               const uint2* __restrict__ ovf,
                                               const float* __restrict__ q2g,
                                               const float* __restrict__ x2maxf,
                                               int* __restrict__ out) {
    int q = blockIdx.x, tid = threadIdx.x;
    __shared__ unsigned eK[TOTC];        // 23-bit approx keys
    __shared__ int eR[TOTC];
    __shared__ int sR[MAXS];
    __shared__ float sKey[MAXS];
    __shared__ int sLab[MAXS];
    __shared__ float qs[64];
    __shared__ int tot, cnt, ns, nw, nt;
    __shared__ unsigned cutS;
    __shared__ float wKey[34];
    __shared__ int wLab[34];
    __shared__ int tIdx[64];
    __shared__ int tLab[64];

    if (tid == 0) { tot = 0; ns = 0; nw = 0; nt = 0; }
    if (tid < 64) qs[tid] = Qm[(long)q * 64 + tid];
    __syncthreads();

    int qh = q >> 9, ql = q & 511;
    // gather from block-exclusive pools (512 chunks x this query-half)
    for (int c2 = tid; c2 < NCHUNK; c2 += 256) {
        int b = (c2 << 1) | qh;
        unsigned lc = pcnt[((long)b << 9) + ql];
        if (lc) {
            long base = (((long)b << 9) + ql) * LCAP;
            uint4 a = *(const uint4*)&pool[base];
            uint4 bb = *(const uint4*)&pool[base + 4];
            int p = atomicAdd(&tot, (int)lc);
            int rbase = c2 * CHROWS2;
#pragma unroll
            for (int i = 0; i < LCAP; i++) {
                unsigned e = (i == 0) ? a.x : (i == 1) ? a.y : (i == 2) ? a.z :
                             (i == 3) ? a.w : (i == 4) ? bb.x : (i == 5) ? bb.y :
                             (i == 6) ? bb.z : bb.w;
                int p2 = p + i;
                if ((unsigned)i < lc && p2 < TOTC) {
                    eK[p2] = e >> 9;
                    eR[p2] = rbase + (int)(e & 511u);
                }
            }
        }
    }
    int ov = min((int)ovfcnt[q], OVFCAP);
    for (int i = tid; i < ov; i += 256) {
        uint2 e = ovf[q * OVFCAP + i];
        int p = atomicAdd(&tot, 1);
        if (p < TOTC) { eK[p] = e.x; eR[p] = (int)e.y; }
    }
    __syncthreads();
    int T = min(tot, TOTC);

    // bisect 23-bit approx keys for the 32nd smallest
    unsigned mk[16];
#pragma unroll
    for (int m = 0; m < 16; m++) { int i = tid + (m << 8); mk[m] = (i < T) ? eK[i] : 0xFFFFFFFFu; }
    unsigned lo = 0, hi = 0x7FFFFFu;
    for (int it = 0; it < 23; ++it) {
        __syncthreads();
        if (tid == 0) cnt = 0;
        __syncthreads();
        unsigned mid = (lo + hi) >> 1;
        int c = 0;
#pragma unroll
        for (int m = 0; m < 16; m++) c += (mk[m] <= mid) ? 1 : 0;
#pragma unroll
        for (int d = 1; d < 64; d <<= 1) c += __shfl_xor(c, d);
        if ((tid & 63) == 0) atomicAdd(&cnt, c);
        __syncthreads();
        if (cnt >= KSEL) hi = mid; else lo = mid + 1;
    }
    float q2v = q2g[q];
    if (tid == 0) {
        unsigned vv = min(hi + 1u, 0x7FFFFFu);
        float tf = funmap(vv << 9);
        float err = 0.004f * sqrtf(q2v * (*x2maxf)) + 0.1f;   // 2x f16 key error + margin
        cutS = min((fmap(tf + err) >> 9) + 1u, 0x7FFFFFu);
    }
    __syncthreads();
    unsigned cut = cutS;
    for (int i = tid; i < T; i += 256)
        if (eK[i] <= cut) { int p = atomicAdd(&ns, 1); if (p < MAXS) sR[p] = eR[i]; }
    __syncthreads();
    int NS = min(ns, MAXS);

    // exact fp32 re-rank of survivors
    for (int i = tid; i < NS; i += 256) {
        int row = sR[i];
        const float4* xr = (const float4*)(X + (long)row * 64);
        const float4* qr = (const float4*)qs;
        float dot = 0.f;
#pragma unroll
        for (int k4 = 0; k4 < 16; k4++) {
            float4 xv = xr[k4], qv = qr[k4];
            dot += qv.x * xv.x + qv.y * xv.y + qv.z * xv.z + qv.w * xv.w;
        }
        sKey[i] = x2[row] - 2.f * dot;
        sLab[i] = labels[row];
    }
    __syncthreads();

    // exact 32nd smallest among survivors (32-step bisection)
    unsigned uk[6];
#pragma unroll
    for (int m = 0; m < 6; m++) { int i = tid + (m << 8); uk[m] = (i < NS) ? fmap(sKey[i]) : 0xFFFFFFFFu; }
    unsigned lo2 = 0u, hi2 = 0xFFFFFFFFu;
    for (int it = 0; it < 32; ++it) {
        __syncthreads();
        if (tid == 0) cnt = 0;
        __syncthreads();
        unsigned mid = lo2 + ((hi2 - lo2) >> 1);
        int c = 0;
#pragma unroll
        for (int m = 0; m < 6; m++) c += (uk[m] <= mid) ? 1 : 0;
#pragma unroll
        for (int d = 1; d < 64; d <<= 1) c += __shfl_xor(c, d);
        if ((tid & 63) == 0) atomicAdd(&cnt, c);
        __syncthreads();
        if (cnt >= KSEL) hi2 = mid; else lo2 = mid + 1;
    }
    unsigned T32 = hi2;   // count(<T32) <= 31, count(<=T32) >= 32

#pragma unroll
    for (int m = 0; m < 6; m++) {
        int i = tid + (m << 8);
        if (i < NS) {
            if (uk[m] < T32) {
                int p = atomicAdd(&nw, 1);
                if (p < 34) { wKey[p] = sKey[i]; wLab[p] = sLab[i]; }
            } else if (uk[m] == T32) {
                int p = atomicAdd(&nt, 1);
                if (p < 64) { tIdx[p] = sR[i]; tLab[p] = sLab[i]; }
            }
        }
    }
    __syncthreads();

    if (tid == 0) {
        float votes[NCLS] = {0.f, 0.f, 0.f, 0.f, 0.f, 0.f, 0.f, 0.f, 0.f, 0.f};
        int NW = min(nw, 32);
        for (int i = 0; i < NW; i++) {
            float dist = q2v + wKey[i];
            if (dist < 0.f) dist = 0.f;
            if (dist == 0.f) dist = 0.1f;
            votes[wLab[i]] += 1.f / dist;
        }
        int need = KSEL - NW;
        int NT = min(nt, 64);
        float tkey = funmap(T32);
        float dist = q2v + tkey;
        if (dist < 0.f) dist = 0.f;
        if (dist == 0.f) dist = 0.1f;
        float twgt = 1.f / dist;
        for (int t = 0; t < need && t < NT; t++) {   // ties: smallest index first
            int best = -1, bi = 0x7FFFFFFF;
            for (int u = 0; u < NT; u++)
                if (tIdx[u] < bi) { bi = tIdx[u]; best = u; }
            if (best < 0) break;
            votes[tLab[best]] += twgt;
            tIdx[best] = 0x7FFFFFFF;
        }
        float bv = votes[0];
        int bc = 0;
#pragma unroll
        for (int c = 1; c < NCLS; c++)
            if (votes[c] > bv) { bv = votes[c]; bc = c; }
        out[q] = bc;
    }
}

extern "C" void kernel_launch(void* const* d_in, const int* in_sizes, int n_in,
                              void* d_out, int out_size, void* d_ws, size_t ws_size,
                              hipStream_t stream) {
    const float* Qm = (const float*)d_in[0];
    const float* X = (const float*)d_in[1];
    const int* labels = (const int*)d_in[2];
    char* ws = (char*)d_ws;
    // ws layout (end = 47,527,488 B; proven ws_size >= 52,017,408):
    // [0,800000)            x2     float[200000]
    // [800000,804096)       tqw    float[1024]
    // [804096,808192)       q2g    float[1024]
    // [808192,808196)       x2maxf float
    // [808256,820756)       bmax   float[3125]
    // [820800,2917952)      pcnt   u32[1024*512]
    // [2917952,2922048)     ovfcnt u32[1024]
    // [2922048,5019200)     ovf    uint2[1024*256]
    // [5019200,21796416)    keys u16[1024*8192] ALIASED WITH pool u32[1024*512*8]
    // [21796416,47396416)   Xh f16[200000*64]
    // [47396416,47527488)   Qh f16[1024*64]
    float* x2 = (float*)(ws + 0);
    float* tqw = (float*)(ws + 800000);
    float* q2g = (float*)(ws + 804096);
    float* x2maxf = (float*)(ws + 808192);
    float* bmax = (float*)(ws + 808256);
    unsigned* pcnt = (unsigned*)(ws + 820800);
    unsigned* ovfcnt = (unsigned*)(ws + 2917952);
    uint2* ovf = (uint2*)(ws + 2922048);
    unsigned short* keys = (unsigned short*)(ws + 5019200);
    unsigned* pool = (unsigned*)(ws + 5019200);
    short* Xh = (short*)(ws + 21796416);
    short* Qh = (short*)(ws + 47396416);
    int* out = (int*)d_out;

    hipMemsetAsync(ovfcnt, 0, 4096, stream);
    k_prep<<<NPB, 512, 0, stream>>>(X, x2, bmax, Xh);
    k_max<<<1, 256, 0, stream>>>(bmax, x2maxf);
    k_cvt<<<32, 256, 0, stream>>>(Qm, Qh);
    k_dist<1><<<2 * (SAMPLES / SROWS), 512, 0, stream>>>(Xh, Qh, x2, tqw, pcnt, pool, ovfcnt, ovf, keys);
    k_sel<<<NQ, 256, 0, stream>>>(keys, Qm, x2maxf, tqw, q2g);
    k_dist<0><<<NBLK0, 512, 0, stream>>>(Xh, Qh, x2, tqw, pcnt, pool, ovfcnt, ovf, keys);
    k_merge<<<NQ, 256, 0, stream>>>(Qm, X, x2, labels, pcnt, pool, ovfcnt, ovf, q2g, x2maxf, out);
}